// Round 7
// baseline (312.415 us; speedup 1.0000x reference)
//
#include <hip/hip_runtime.h>

typedef long long i64;
typedef __attribute__((ext_vector_type(8))) short short8;
typedef __attribute__((ext_vector_type(4))) unsigned short us4;
typedef __attribute__((ext_vector_type(4))) float f32x4;

__device__ __forceinline__ unsigned short bf16_rtn(float x) {
  unsigned u = __float_as_uint(x);
  unsigned r = (u + 0x7FFFu + ((u >> 16) & 1u)) >> 16;
  return (unsigned short)r;
}
__device__ __forceinline__ float bf16_to_f(unsigned short h) {
  return __uint_as_float(((unsigned)h) << 16);
}

// ---------------------------------------------------------------------------
// Per-wave edge-dtype detection (int64 storage => odd int32 words of row 0
// are all zero; for int32 data they are edge values, P(64 zeros) ~ 0).
// ---------------------------------------------------------------------------
__device__ __forceinline__ bool wave_is64(const int* __restrict__ ei32, i64 e0) {
  int probe = ei32[2 * e0 + 1];
  return __ballot(probe != 0) == 0ULL;
}

// ---------------------------------------------------------------------------
// init: zero counts[N] + weight split/transpose (3 weights) in one launch.
// ---------------------------------------------------------------------------
__global__ __launch_bounds__(256) void init_split_kernel(
    int* __restrict__ counts, int N,
    const float* __restrict__ Wa, unsigned short* __restrict__ wha, unsigned short* __restrict__ wla,
    const float* __restrict__ Wb, unsigned short* __restrict__ whb, unsigned short* __restrict__ wlb,
    const float* __restrict__ Wc, unsigned short* __restrict__ whc, unsigned short* __restrict__ wlc) {
  int nbInit = (N + 255) >> 8;
  if ((int)blockIdx.x < nbInit) {
    int i = blockIdx.x * 256 + threadIdx.x;
    if (i < N) counts[i] = 0;
    return;
  }
  int bb = blockIdx.x - nbInit;                   // 0..191
  int b = bb >> 6;
  int t = (bb & 63) * 256 + threadIdx.x;          // 0..16383
  const float* W = (b == 0) ? Wa : (b == 1) ? Wb : Wc;
  unsigned short* wh = (b == 0) ? wha : (b == 1) ? whb : whc;
  unsigned short* wl = (b == 0) ? wla : (b == 1) ? wlb : wlc;
  int c = t >> 7, k = t & 127;
  float w = W[k * 128 + c];
  unsigned short hi = bf16_rtn(w);
  unsigned short lo = bf16_rtn(w - bf16_to_f(hi));
  wh[c * 128 + k] = hi;
  wl[c * 128 + k] = lo;
}

// ---------------------------------------------------------------------------
// Narrow edge index to int32 once: s32[e], d32[e].
// ---------------------------------------------------------------------------
__global__ __launch_bounds__(256) void conv_edges_kernel(const int* __restrict__ ei32, int E,
                                                         int* __restrict__ s32, int* __restrict__ d32) {
  int e = blockIdx.x * 256 + threadIdx.x;
  if (e >= E) return;
  bool is64 = wave_is64(ei32, e);
  s32[e] = is64 ? ei32[2 * (i64)e] : ei32[e];
  d32[e] = is64 ? ei32[2 * ((i64)E + e)] : ei32[(i64)E + e];
}

// ---------------------------------------------------------------------------
// Destination-sharded degree count on narrowed d32.
// ---------------------------------------------------------------------------
__global__ __launch_bounds__(256) void count_kernel(const int* __restrict__ d32,
                                                    int* __restrict__ counts, int E, int N) {
  int shard = blockIdx.x & 7;
  int chunk = blockIdx.x >> 3;
  int ns = (N + 7) >> 3;
  int lo = shard * ns, hi = min(lo + ns, N);
  int base = chunk * 2048;
  int t = threadIdx.x;
#pragma unroll
  for (int j = 0; j < 8; ++j) {
    int e = base + j * 256 + t;
    if (e >= E) break;
    int d = d32[e];
    if (d >= lo && d < hi) atomicAdd(&counts[d], 1);
  }
}

// ---------------------------------------------------------------------------
// Device-wide exclusive scan of counts (3 phases, 1024 elems per block).
// ---------------------------------------------------------------------------
__global__ __launch_bounds__(256) void psum_kernel(const int* __restrict__ counts,
                                                   int* __restrict__ bsum, int N) {
  int base = blockIdx.x * 1024 + threadIdx.x * 4;
  int s = 0;
#pragma unroll
  for (int j = 0; j < 4; ++j) {
    int i = base + j;
    if (i < N) s += counts[i];
  }
#pragma unroll
  for (int off = 32; off > 0; off >>= 1) s += __shfl_down(s, off);
  __shared__ int ws[4];
  int wid = threadIdx.x >> 6;
  if ((threadIdx.x & 63) == 0) ws[wid] = s;
  __syncthreads();
  if (threadIdx.x == 0) bsum[blockIdx.x] = ws[0] + ws[1] + ws[2] + ws[3];
}

__global__ __launch_bounds__(1024) void bscan_kernel(int* __restrict__ bsum, int nb,
                                                     int* __restrict__ offs_last, int E) {
  __shared__ int sh[1024];
  int tid = threadIdx.x;
  int v = (tid < nb) ? bsum[tid] : 0;
  sh[tid] = v;
  __syncthreads();
  for (int off = 1; off < 1024; off <<= 1) {
    int t = (tid >= off) ? sh[tid - off] : 0;
    __syncthreads();
    sh[tid] += t;
    __syncthreads();
  }
  if (tid < nb) bsum[tid] = sh[tid] - v;  // exclusive
  if (tid == 0) offs_last[0] = E;
}

__global__ __launch_bounds__(256) void scatter_kernel(
    const int* __restrict__ counts, const int* __restrict__ bsum,
    int* __restrict__ offs, int* __restrict__ cursor, float* __restrict__ dinv, int N) {
  __shared__ int wsum[4];
  int tid = threadIdx.x;
  int base = blockIdx.x * 1024 + tid * 4;
  int c[4];
  int s = 0;
#pragma unroll
  for (int j = 0; j < 4; ++j) {
    int i = base + j;
    c[j] = (i < N) ? counts[i] : 0;
    s += c[j];
  }
  int lane = tid & 63, wid = tid >> 6;
  int incl = s;
#pragma unroll
  for (int off = 1; off < 64; off <<= 1) {
    int t = __shfl_up(incl, off);
    if (lane >= off) incl += t;
  }
  if (lane == 63) wsum[wid] = incl;
  __syncthreads();
  int wo = 0;
  for (int wq = 0; wq < wid; ++wq) wo += wsum[wq];
  int excl = incl - s + wo + bsum[blockIdx.x];
#pragma unroll
  for (int j = 0; j < 4; ++j) {
    int i = base + j;
    if (i < N) {
      offs[i] = excl;
      cursor[i] = excl;
      dinv[i] = rsqrtf((float)c[j] + 1.0f);
      excl += c[j];
    }
  }
}

// ---------------------------------------------------------------------------
// Destination-sharded CSR fill on narrowed s32/d32.
// ---------------------------------------------------------------------------
__global__ __launch_bounds__(256) void fill_kernel(const int* __restrict__ s32,
                                                   const int* __restrict__ d32,
                                                   int* __restrict__ cursor,
                                                   int* __restrict__ col, int E, int N) {
  int shard = blockIdx.x & 7;
  int chunk = blockIdx.x >> 3;
  int ns = (N + 7) >> 3;
  int lo = shard * ns, hi = min(lo + ns, N);
  int base = chunk * 2048;
  int t = threadIdx.x;
#pragma unroll
  for (int j = 0; j < 8; ++j) {
    int e = base + j * 256 + t;
    if (e >= E) break;
    int d = d32[e];
    if (d >= lo && d < hi) {
      int pos = atomicAdd(&cursor[d], 1);
      col[pos] = s32[e];
    }
  }
}

// ---------------------------------------------------------------------------
// LDS-free split-bf16 MFMA GEMM: C[N,128] = A[N,128] @ W[128,128].
// MODE 0: hb (channel-blocked [4][N][32] bf16) = acc * dinv[row]
// MODE 1: out fp32 [N][128]                    = relu(acc + bias[col])
// ---------------------------------------------------------------------------
template <int MODE>
__global__ __launch_bounds__(256, 4) void gemm_mfma(
    const float* __restrict__ A, const unsigned short* __restrict__ WhT,
    const unsigned short* __restrict__ WlT, const float* __restrict__ aux,
    void* __restrict__ outv, int N) {
  int tid = threadIdx.x;
  int wid = tid >> 6, lane = tid & 63;
  int lr = lane & 15, kg = (lane >> 4) * 8;
  int rowbase = blockIdx.x * 128 + wid * 32;

  f32x4 acc[2][8];
#pragma unroll
  for (int tr = 0; tr < 2; ++tr)
#pragma unroll
    for (int tc = 0; tc < 8; ++tc) acc[tr][tc] = (f32x4){0.f, 0.f, 0.f, 0.f};

  int r[2] = {rowbase + lr, rowbase + 16 + lr};

  for (int kc = 0; kc < 128; kc += 32) {
    int k0 = kc + kg;
    short8 afh[2], afl[2];
#pragma unroll
    for (int tr = 0; tr < 2; ++tr) {
      float4 va = make_float4(0.f, 0.f, 0.f, 0.f), vb = va;
      if (r[tr] < N) {
        const float* p = &A[(i64)r[tr] * 128 + k0];
        va = *reinterpret_cast<const float4*>(p);
        vb = *reinterpret_cast<const float4*>(p + 4);
      }
      float xs[8] = {va.x, va.y, va.z, va.w, vb.x, vb.y, vb.z, vb.w};
#pragma unroll
      for (int j = 0; j < 8; ++j) {
        unsigned short h = bf16_rtn(xs[j]);
        afh[tr][j] = (short)h;
        afl[tr][j] = (short)bf16_rtn(xs[j] - bf16_to_f(h));
      }
    }
#pragma unroll
    for (int tc = 0; tc < 8; ++tc) {
      int c = tc * 16 + lr;
      short8 bfh = *reinterpret_cast<const short8*>(&WhT[c * 128 + k0]);
      short8 bfl = *reinterpret_cast<const short8*>(&WlT[c * 128 + k0]);
#pragma unroll
      for (int tr = 0; tr < 2; ++tr) {
        acc[tr][tc] = __builtin_amdgcn_mfma_f32_16x16x32_bf16(afh[tr], bfh, acc[tr][tc], 0, 0, 0);
        acc[tr][tc] = __builtin_amdgcn_mfma_f32_16x16x32_bf16(afl[tr], bfh, acc[tr][tc], 0, 0, 0);
        acc[tr][tc] = __builtin_amdgcn_mfma_f32_16x16x32_bf16(afh[tr], bfl, acc[tr][tc], 0, 0, 0);
      }
    }
  }

  // epilogue (C/D layout: col = tc*16 + (lane&15), row = tr*16 + (lane>>4)*4 + reg)
  if (MODE == 0) {
    unsigned short* hb = (unsigned short*)outv;
#pragma unroll
    for (int tr = 0; tr < 2; ++tr) {
#pragma unroll
      for (int reg = 0; reg < 4; ++reg) {
        int row = rowbase + tr * 16 + (lane >> 4) * 4 + reg;
        if (row >= N) continue;
        float dv = aux[row];
#pragma unroll
        for (int tc = 0; tc < 8; ++tc) {
          int colg = tc * 16 + lr;
          // channel-blocked: [chunk][N][32]
          hb[(i64)(colg >> 5) * N * 32 + (i64)row * 32 + (colg & 31)] =
              bf16_rtn(acc[tr][tc][reg] * dv);
        }
      }
    }
  } else {
    float* out = (float*)outv;
#pragma unroll
    for (int tr = 0; tr < 2; ++tr) {
#pragma unroll
      for (int reg = 0; reg < 4; ++reg) {
        int row = rowbase + tr * 16 + (lane >> 4) * 4 + reg;
        if (row >= N) continue;
#pragma unroll
        for (int tc = 0; tc < 8; ++tc) {
          int colg = tc * 16 + lr;
          out[(i64)row * 128 + colg] = fmaxf(acc[tr][tc][reg] + aux[colg], 0.f);
        }
      }
    }
  }
}

// ---------------------------------------------------------------------------
// Channel-tiled aggregation over blocked bf16 H' ([4][N][32]):
//   out[v][128] = (relu?)( dinv[v]*(H'[v] + sum_s H'[s]) + b )
// 4 chunk-major passes in one launch; per pass the 3.2MB slab is L2-resident.
// One wave per node: lane = edge_slot(0..7) x ch_lane(0..7, us4 = 4ch).
// 8 edges gathered in parallel (one 64B line each), shfl_xor reduction.
// ---------------------------------------------------------------------------
template <int RELU>
__global__ __launch_bounds__(256) void agg_bf16(
    const unsigned short* __restrict__ hb, const int* __restrict__ col,
    const int* __restrict__ offs, const float* __restrict__ dinv,
    const float* __restrict__ bias, float* __restrict__ out, int N, int bpp) {
  int chunk = blockIdx.x / bpp;
  int v = (blockIdx.x % bpp) * 4 + (threadIdx.x >> 6);
  if (v >= N) return;
  int lane = threadIdx.x & 63;
  int es = lane >> 3;            // edge slot 0..7
  int cl = lane & 7;             // channel lane: 4 channels each
  const unsigned short* slab = hb + (i64)chunk * N * 32;

  float a0 = 0.f, a1 = 0.f, a2 = 0.f, a3 = 0.f;
  if (es == 0) {  // self-loop term
    us4 sv = *reinterpret_cast<const us4*>(&slab[(i64)v * 32 + cl * 4]);
    a0 = bf16_to_f(sv[0]); a1 = bf16_to_f(sv[1]);
    a2 = bf16_to_f(sv[2]); a3 = bf16_to_f(sv[3]);
  }
  int beg = offs[v], end = offs[v + 1];
  for (int i = beg + es; i < end; i += 8) {
    int s = col[i];
    us4 u = *reinterpret_cast<const us4*>(&slab[(i64)s * 32 + cl * 4]);
    a0 += bf16_to_f(u[0]); a1 += bf16_to_f(u[1]);
    a2 += bf16_to_f(u[2]); a3 += bf16_to_f(u[3]);
  }
  // reduce across the 8 edge slots (lanes v ^ 8,16,32)
#pragma unroll
  for (int m = 8; m < 64; m <<= 1) {
    a0 += __shfl_xor(a0, m);
    a1 += __shfl_xor(a1, m);
    a2 += __shfl_xor(a2, m);
    a3 += __shfl_xor(a3, m);
  }
  if (es == 0) {
    float dv = dinv[v];
    float4 b = *reinterpret_cast<const float4*>(&bias[chunk * 32 + cl * 4]);
    float4 rr;
    rr.x = fmaf(a0, dv, b.x);
    rr.y = fmaf(a1, dv, b.y);
    rr.z = fmaf(a2, dv, b.z);
    rr.w = fmaf(a3, dv, b.w);
    if (RELU) {
      rr.x = fmaxf(rr.x, 0.f); rr.y = fmaxf(rr.y, 0.f);
      rr.z = fmaxf(rr.z, 0.f); rr.w = fmaxf(rr.w, 0.f);
    }
    *reinterpret_cast<float4*>(&out[(i64)v * 128 + chunk * 32 + cl * 4]) = rr;
  }
}

// ---------------------------------------------------------------------------
extern "C" void kernel_launch(void* const* d_in, const int* in_sizes, int n_in,
                              void* d_out, int out_size, void* d_ws, size_t ws_size,
                              hipStream_t stream) {
  const float* x  = (const float*)d_in[0];
  const int*   ei = (const int*)d_in[1];
  const float* W1 = (const float*)d_in[2];
  const float* b1 = (const float*)d_in[3];
  const float* W2 = (const float*)d_in[4];
  const float* b2 = (const float*)d_in[5];
  const float* Wd = (const float*)d_in[6];
  const float* bd = (const float*)d_in[7];
  int N = in_sizes[0] / 128;
  int E = in_sizes[1] / 2;
  float* out = (float*)d_out;

  // workspace layout
  char* w = (char*)d_ws;
  float*          z    = (float*)w;                        // N*128 fp32
  unsigned short* wh1  = (unsigned short*)(z + (i64)N * 128);
  unsigned short* wl1  = wh1 + 16384;
  unsigned short* wh2  = wl1 + 16384;
  unsigned short* wl2  = wh2 + 16384;
  unsigned short* whd  = wl2 + 16384;
  unsigned short* wld  = whd + 16384;
  int*   counts = (int*)(wld + 16384);
  int*   offs   = counts + N;                              // N+1
  int*   cursor = offs + N + 1;                            // N
  int*   col    = cursor + N;                              // E
  int*   s32    = col + E;                                 // E
  int*   d32    = s32 + E;                                 // E
  float* dinv   = (float*)(d32 + E);                       // N
  int*   bsum   = (int*)(dinv + N);                        // <=1024
  unsigned short* hb = (unsigned short*)d_out;  // blocked bf16 H' [4][N][32]

  int nb = (N + 1023) / 1024;
  int nbInit = (N + 255) / 256;
  int cb = (E + 2047) / 2048;

  init_split_kernel<<<nbInit + 192, 256, 0, stream>>>(counts, N,
      W1, wh1, wl1, W2, wh2, wl2, Wd, whd, wld);
  conv_edges_kernel<<<(E + 255) / 256, 256, 0, stream>>>(ei, E, s32, d32);
  count_kernel<<<8 * cb, 256, 0, stream>>>(d32, counts, E, N);
  psum_kernel<<<nb, 256, 0, stream>>>(counts, bsum, N);
  bscan_kernel<<<1, 1024, 0, stream>>>(bsum, nb, offs + N, E);
  scatter_kernel<<<nb, 256, 0, stream>>>(counts, bsum, offs, cursor, dinv, N);
  fill_kernel<<<8 * cb, 256, 0, stream>>>(s32, d32, cursor, col, E, N);

  int gblocks = (N + 127) / 128;
  int bpp = (N + 3) / 4;        // agg blocks per chunk-pass
  int ablocks = 4 * bpp;

  // conv1: hb = bf16((x@W1)*dinv) blocked ; z = relu(dinv*(hb_v + sum) + b1)
  gemm_mfma<0><<<gblocks, 256, 0, stream>>>(x, wh1, wl1, dinv, hb, N);
  agg_bf16<1><<<ablocks, 256, 0, stream>>>(hb, col, offs, dinv, b1, z, N, bpp);
  // conv2
  gemm_mfma<0><<<gblocks, 256, 0, stream>>>(z, wh2, wl2, dinv, hb, N);
  agg_bf16<0><<<ablocks, 256, 0, stream>>>(hb, col, offs, dinv, b2, z, N, bpp);
  // decoder: out = relu(z @ Wd + bd)
  gemm_mfma<1><<<gblocks, 256, 0, stream>>>(z, whd, wld, bd, out, N);
}

// Round 9
// 253.698 us; speedup vs baseline: 1.2314x; 1.2314x over previous
//
#include <hip/hip_runtime.h>

typedef long long i64;
typedef __attribute__((ext_vector_type(8))) short short8;
typedef __attribute__((ext_vector_type(4))) unsigned short us4;
typedef __attribute__((ext_vector_type(4))) float f32x4;

__device__ __forceinline__ unsigned short bf16_rtn(float x) {
  unsigned u = __float_as_uint(x);
  unsigned r = (u + 0x7FFFu + ((u >> 16) & 1u)) >> 16;
  return (unsigned short)r;
}
__device__ __forceinline__ float bf16_to_f(unsigned short h) {
  return __uint_as_float(((unsigned)h) << 16);
}

// ---------------------------------------------------------------------------
// Per-wave edge-dtype detection (int64 storage => odd int32 words of row 0
// are all zero; for int32 data they are edge values, P(64 zeros) ~ 0).
// ---------------------------------------------------------------------------
__device__ __forceinline__ bool wave_is64(const int* __restrict__ ei32, i64 e0) {
  int probe = ei32[2 * e0 + 1];
  return __ballot(probe != 0) == 0ULL;
}

// ---------------------------------------------------------------------------
// init: zero counts[N] + weight split/transpose (3 weights) in one launch.
// ---------------------------------------------------------------------------
__global__ __launch_bounds__(256) void init_split_kernel(
    int* __restrict__ counts, int N,
    const float* __restrict__ Wa, unsigned short* __restrict__ wha, unsigned short* __restrict__ wla,
    const float* __restrict__ Wb, unsigned short* __restrict__ whb, unsigned short* __restrict__ wlb,
    const float* __restrict__ Wc, unsigned short* __restrict__ whc, unsigned short* __restrict__ wlc) {
  int nbInit = (N + 255) >> 8;
  if ((int)blockIdx.x < nbInit) {
    int i = blockIdx.x * 256 + threadIdx.x;
    if (i < N) counts[i] = 0;
    return;
  }
  int bb = blockIdx.x - nbInit;                   // 0..191
  int b = bb >> 6;
  int t = (bb & 63) * 256 + threadIdx.x;          // 0..16383
  const float* W = (b == 0) ? Wa : (b == 1) ? Wb : Wc;
  unsigned short* wh = (b == 0) ? wha : (b == 1) ? whb : whc;
  unsigned short* wl = (b == 0) ? wla : (b == 1) ? wlb : wlc;
  int c = t >> 7, k = t & 127;
  float w = W[k * 128 + c];
  unsigned short hi = bf16_rtn(w);
  unsigned short lo = bf16_rtn(w - bf16_to_f(hi));
  wh[c * 128 + k] = hi;
  wl[c * 128 + k] = lo;
}

// ---------------------------------------------------------------------------
// Narrow edge index to int32 once: s32[e], d32[e].
// ---------------------------------------------------------------------------
__global__ __launch_bounds__(256) void conv_edges_kernel(const int* __restrict__ ei32, int E,
                                                         int* __restrict__ s32, int* __restrict__ d32) {
  int e = blockIdx.x * 256 + threadIdx.x;
  if (e >= E) return;
  bool is64 = wave_is64(ei32, e);
  s32[e] = is64 ? ei32[2 * (i64)e] : ei32[e];
  d32[e] = is64 ? ei32[2 * ((i64)E + e)] : ei32[(i64)E + e];
}

// ---------------------------------------------------------------------------
// Destination-sharded degree count on narrowed d32.
// ---------------------------------------------------------------------------
__global__ __launch_bounds__(256) void count_kernel(const int* __restrict__ d32,
                                                    int* __restrict__ counts, int E, int N) {
  int shard = blockIdx.x & 7;
  int chunk = blockIdx.x >> 3;
  int ns = (N + 7) >> 3;
  int lo = shard * ns, hi = min(lo + ns, N);
  int base = chunk * 2048;
  int t = threadIdx.x;
#pragma unroll
  for (int j = 0; j < 8; ++j) {
    int e = base + j * 256 + t;
    if (e >= E) break;
    int d = d32[e];
    if (d >= lo && d < hi) atomicAdd(&counts[d], 1);
  }
}

// ---------------------------------------------------------------------------
// Device-wide exclusive scan of counts (3 phases, 1024 elems per block).
// ---------------------------------------------------------------------------
__global__ __launch_bounds__(256) void psum_kernel(const int* __restrict__ counts,
                                                   int* __restrict__ bsum, int N) {
  int base = blockIdx.x * 1024 + threadIdx.x * 4;
  int s = 0;
#pragma unroll
  for (int j = 0; j < 4; ++j) {
    int i = base + j;
    if (i < N) s += counts[i];
  }
#pragma unroll
  for (int off = 32; off > 0; off >>= 1) s += __shfl_down(s, off);
  __shared__ int ws[4];
  int wid = threadIdx.x >> 6;
  if ((threadIdx.x & 63) == 0) ws[wid] = s;
  __syncthreads();
  if (threadIdx.x == 0) bsum[blockIdx.x] = ws[0] + ws[1] + ws[2] + ws[3];
}

__global__ __launch_bounds__(1024) void bscan_kernel(int* __restrict__ bsum, int nb,
                                                     int* __restrict__ offs_last, int E) {
  __shared__ int sh[1024];
  int tid = threadIdx.x;
  int v = (tid < nb) ? bsum[tid] : 0;
  sh[tid] = v;
  __syncthreads();
  for (int off = 1; off < 1024; off <<= 1) {
    int t = (tid >= off) ? sh[tid - off] : 0;
    __syncthreads();
    sh[tid] += t;
    __syncthreads();
  }
  if (tid < nb) bsum[tid] = sh[tid] - v;  // exclusive
  if (tid == 0) offs_last[0] = E;
}

__global__ __launch_bounds__(256) void scatter_kernel(
    const int* __restrict__ counts, const int* __restrict__ bsum,
    int* __restrict__ offs, int* __restrict__ cursor, float* __restrict__ dinv, int N) {
  __shared__ int wsum[4];
  int tid = threadIdx.x;
  int base = blockIdx.x * 1024 + tid * 4;
  int c[4];
  int s = 0;
#pragma unroll
  for (int j = 0; j < 4; ++j) {
    int i = base + j;
    c[j] = (i < N) ? counts[i] : 0;
    s += c[j];
  }
  int lane = tid & 63, wid = tid >> 6;
  int incl = s;
#pragma unroll
  for (int off = 1; off < 64; off <<= 1) {
    int t = __shfl_up(incl, off);
    if (lane >= off) incl += t;
  }
  if (lane == 63) wsum[wid] = incl;
  __syncthreads();
  int wo = 0;
  for (int wq = 0; wq < wid; ++wq) wo += wsum[wq];
  int excl = incl - s + wo + bsum[blockIdx.x];
#pragma unroll
  for (int j = 0; j < 4; ++j) {
    int i = base + j;
    if (i < N) {
      offs[i] = excl;
      cursor[i] = excl;
      dinv[i] = rsqrtf((float)c[j] + 1.0f);
      excl += c[j];
    }
  }
}

// ---------------------------------------------------------------------------
// Destination-sharded CSR fill on narrowed s32/d32.
// ---------------------------------------------------------------------------
__global__ __launch_bounds__(256) void fill_kernel(const int* __restrict__ s32,
                                                   const int* __restrict__ d32,
                                                   int* __restrict__ cursor,
                                                   int* __restrict__ col, int E, int N) {
  int shard = blockIdx.x & 7;
  int chunk = blockIdx.x >> 3;
  int ns = (N + 7) >> 3;
  int lo = shard * ns, hi = min(lo + ns, N);
  int base = chunk * 2048;
  int t = threadIdx.x;
#pragma unroll
  for (int j = 0; j < 8; ++j) {
    int e = base + j * 256 + t;
    if (e >= E) break;
    int d = d32[e];
    if (d >= lo && d < hi) {
      int pos = atomicAdd(&cursor[d], 1);
      col[pos] = s32[e];
    }
  }
}

// ---------------------------------------------------------------------------
// LDS-free split-bf16 MFMA GEMM: C[N,128] = A[N,128] @ W[128,128].
// MODE 0: hb (channel-blocked [4][N][32] bf16) = acc * dinv[row]
// MODE 1: out fp32 [N][128]                    = relu(acc + bias[col])
// ---------------------------------------------------------------------------
template <int MODE>
__global__ __launch_bounds__(256, 4) void gemm_mfma(
    const float* __restrict__ A, const unsigned short* __restrict__ WhT,
    const unsigned short* __restrict__ WlT, const float* __restrict__ aux,
    void* __restrict__ outv, int N) {
  int tid = threadIdx.x;
  int wid = tid >> 6, lane = tid & 63;
  int lr = lane & 15, kg = (lane >> 4) * 8;
  int rowbase = blockIdx.x * 128 + wid * 32;

  f32x4 acc[2][8];
#pragma unroll
  for (int tr = 0; tr < 2; ++tr)
#pragma unroll
    for (int tc = 0; tc < 8; ++tc) acc[tr][tc] = (f32x4){0.f, 0.f, 0.f, 0.f};

  int r[2] = {rowbase + lr, rowbase + 16 + lr};

  for (int kc = 0; kc < 128; kc += 32) {
    int k0 = kc + kg;
    short8 afh[2], afl[2];
#pragma unroll
    for (int tr = 0; tr < 2; ++tr) {
      float4 va = make_float4(0.f, 0.f, 0.f, 0.f), vb = va;
      if (r[tr] < N) {
        const float* p = &A[(i64)r[tr] * 128 + k0];
        va = *reinterpret_cast<const float4*>(p);
        vb = *reinterpret_cast<const float4*>(p + 4);
      }
      float xs[8] = {va.x, va.y, va.z, va.w, vb.x, vb.y, vb.z, vb.w};
#pragma unroll
      for (int j = 0; j < 8; ++j) {
        unsigned short h = bf16_rtn(xs[j]);
        afh[tr][j] = (short)h;
        afl[tr][j] = (short)bf16_rtn(xs[j] - bf16_to_f(h));
      }
    }
#pragma unroll
    for (int tc = 0; tc < 8; ++tc) {
      int c = tc * 16 + lr;
      short8 bfh = *reinterpret_cast<const short8*>(&WhT[c * 128 + k0]);
      short8 bfl = *reinterpret_cast<const short8*>(&WlT[c * 128 + k0]);
#pragma unroll
      for (int tr = 0; tr < 2; ++tr) {
        acc[tr][tc] = __builtin_amdgcn_mfma_f32_16x16x32_bf16(afh[tr], bfh, acc[tr][tc], 0, 0, 0);
        acc[tr][tc] = __builtin_amdgcn_mfma_f32_16x16x32_bf16(afl[tr], bfh, acc[tr][tc], 0, 0, 0);
        acc[tr][tc] = __builtin_amdgcn_mfma_f32_16x16x32_bf16(afh[tr], bfl, acc[tr][tc], 0, 0, 0);
      }
    }
  }

  // epilogue (C/D layout: col = tc*16 + (lane&15), row = tr*16 + (lane>>4)*4 + reg)
  if (MODE == 0) {
    unsigned short* hb = (unsigned short*)outv;
#pragma unroll
    for (int tr = 0; tr < 2; ++tr) {
#pragma unroll
      for (int reg = 0; reg < 4; ++reg) {
        int row = rowbase + tr * 16 + (lane >> 4) * 4 + reg;
        if (row >= N) continue;
        float dv = aux[row];
#pragma unroll
        for (int tc = 0; tc < 8; ++tc) {
          int colg = tc * 16 + lr;
          hb[(i64)(colg >> 5) * N * 32 + (i64)row * 32 + (colg & 31)] =
              bf16_rtn(acc[tr][tc][reg] * dv);
        }
      }
    }
  } else {
    float* out = (float*)outv;
#pragma unroll
    for (int tr = 0; tr < 2; ++tr) {
#pragma unroll
      for (int reg = 0; reg < 4; ++reg) {
        int row = rowbase + tr * 16 + (lane >> 4) * 4 + reg;
        if (row >= N) continue;
#pragma unroll
        for (int tc = 0; tc < 8; ++tc) {
          int colg = tc * 16 + lr;
          out[(i64)row * 128 + colg] = fmaxf(acc[tr][tc][reg] + aux[colg], 0.f);
        }
      }
    }
  }
}

// ---------------------------------------------------------------------------
// Channel-tiled aggregation v2 over blocked bf16 H' ([4][N][32]):
//   out[v][chunk*32..+32] = (relu?)( dinv[v]*(H'[v] + sum_s H'[s]) + b )
// 4 chunk-major passes in one launch; per pass the 3.2MB slab is L2-resident
// per XCD. 8 lanes per node (lane = 4 ch, us4 8B; 64B line per gather),
// 8 nodes/wave, 32 nodes/block, plain serial edge loop (round-6 efficiency).
// Output stored nontemporal so the write stream doesn't evict the slab.
// ---------------------------------------------------------------------------
template <int RELU>
__global__ __launch_bounds__(256) void agg_bf16(
    const unsigned short* __restrict__ hb, const int* __restrict__ col,
    const int* __restrict__ offs, const float* __restrict__ dinv,
    const float* __restrict__ bias, float* __restrict__ out, int N, int bpp) {
  int chunk = blockIdx.x / bpp;
  int t = threadIdx.x;
  int v = (blockIdx.x % bpp) * 32 + (t >> 3);   // 32 nodes per block
  if (v >= N) return;
  int cl = t & 7;                               // 4 channels per lane
  const unsigned short* slab = hb + (i64)chunk * N * 32;

  // self-loop term
  us4 sv = *reinterpret_cast<const us4*>(&slab[(i64)v * 32 + cl * 4]);
  float a0 = bf16_to_f(sv[0]), a1 = bf16_to_f(sv[1]);
  float a2 = bf16_to_f(sv[2]), a3 = bf16_to_f(sv[3]);

  int beg = offs[v], end = offs[v + 1];
  int i = beg;
  for (; i + 1 < end; i += 2) {
    int s0 = col[i], s1 = col[i + 1];
    us4 u0 = *reinterpret_cast<const us4*>(&slab[(i64)s0 * 32 + cl * 4]);
    us4 u1 = *reinterpret_cast<const us4*>(&slab[(i64)s1 * 32 + cl * 4]);
    a0 += bf16_to_f(u0[0]) + bf16_to_f(u1[0]);
    a1 += bf16_to_f(u0[1]) + bf16_to_f(u1[1]);
    a2 += bf16_to_f(u0[2]) + bf16_to_f(u1[2]);
    a3 += bf16_to_f(u0[3]) + bf16_to_f(u1[3]);
  }
  if (i < end) {
    int s0 = col[i];
    us4 u0 = *reinterpret_cast<const us4*>(&slab[(i64)s0 * 32 + cl * 4]);
    a0 += bf16_to_f(u0[0]); a1 += bf16_to_f(u0[1]);
    a2 += bf16_to_f(u0[2]); a3 += bf16_to_f(u0[3]);
  }

  float dv = dinv[v];
  const f32x4* bp = reinterpret_cast<const f32x4*>(&bias[chunk * 32 + cl * 4]);
  f32x4 b = *bp;
  f32x4 rr;
  rr[0] = fmaf(a0, dv, b[0]);
  rr[1] = fmaf(a1, dv, b[1]);
  rr[2] = fmaf(a2, dv, b[2]);
  rr[3] = fmaf(a3, dv, b[3]);
  if (RELU) {
    rr[0] = fmaxf(rr[0], 0.f); rr[1] = fmaxf(rr[1], 0.f);
    rr[2] = fmaxf(rr[2], 0.f); rr[3] = fmaxf(rr[3], 0.f);
  }
  __builtin_nontemporal_store(rr, reinterpret_cast<f32x4*>(&out[(i64)v * 128 + chunk * 32 + cl * 4]));
}

// ---------------------------------------------------------------------------
extern "C" void kernel_launch(void* const* d_in, const int* in_sizes, int n_in,
                              void* d_out, int out_size, void* d_ws, size_t ws_size,
                              hipStream_t stream) {
  const float* x  = (const float*)d_in[0];
  const int*   ei = (const int*)d_in[1];
  const float* W1 = (const float*)d_in[2];
  const float* b1 = (const float*)d_in[3];
  const float* W2 = (const float*)d_in[4];
  const float* b2 = (const float*)d_in[5];
  const float* Wd = (const float*)d_in[6];
  const float* bd = (const float*)d_in[7];
  int N = in_sizes[0] / 128;
  int E = in_sizes[1] / 2;
  float* out = (float*)d_out;

  // workspace layout
  char* w = (char*)d_ws;
  float*          z    = (float*)w;                        // N*128 fp32
  unsigned short* wh1  = (unsigned short*)(z + (i64)N * 128);
  unsigned short* wl1  = wh1 + 16384;
  unsigned short* wh2  = wl1 + 16384;
  unsigned short* wl2  = wh2 + 16384;
  unsigned short* whd  = wl2 + 16384;
  unsigned short* wld  = whd + 16384;
  int*   counts = (int*)(wld + 16384);
  int*   offs   = counts + N;                              // N+1
  int*   cursor = offs + N + 1;                            // N
  int*   col    = cursor + N;                              // E
  int*   s32    = col + E;                                 // E
  int*   d32    = s32 + E;                                 // E
  float* dinv   = (float*)(d32 + E);                       // N
  int*   bsum   = (int*)(dinv + N);                        // <=1024
  unsigned short* hb = (unsigned short*)d_out;  // blocked bf16 H' [4][N][32]

  int nb = (N + 1023) / 1024;
  int nbInit = (N + 255) / 256;
  int cb = (E + 2047) / 2048;

  init_split_kernel<<<nbInit + 192, 256, 0, stream>>>(counts, N,
      W1, wh1, wl1, W2, wh2, wl2, Wd, whd, wld);
  conv_edges_kernel<<<(E + 255) / 256, 256, 0, stream>>>(ei, E, s32, d32);
  count_kernel<<<8 * cb, 256, 0, stream>>>(d32, counts, E, N);
  psum_kernel<<<nb, 256, 0, stream>>>(counts, bsum, N);
  bscan_kernel<<<1, 1024, 0, stream>>>(bsum, nb, offs + N, E);
  scatter_kernel<<<nb, 256, 0, stream>>>(counts, bsum, offs, cursor, dinv, N);
  fill_kernel<<<8 * cb, 256, 0, stream>>>(s32, d32, cursor, col, E, N);

  int gblocks = (N + 127) / 128;
  int bpp = (N + 31) / 32;      // agg blocks per chunk-pass (32 nodes/block)
  int ablocks = 4 * bpp;

  // conv1: hb = bf16((x@W1)*dinv) blocked ; z = relu(dinv*(hb_v + sum) + b1)
  gemm_mfma<0><<<gblocks, 256, 0, stream>>>(x, wh1, wl1, dinv, hb, N);
  agg_bf16<1><<<ablocks, 256, 0, stream>>>(hb, col, offs, dinv, b1, z, N, bpp);
  // conv2
  gemm_mfma<0><<<gblocks, 256, 0, stream>>>(z, wh2, wl2, dinv, hb, N);
  agg_bf16<0><<<ablocks, 256, 0, stream>>>(hb, col, offs, dinv, b2, z, N, bpp);
  // decoder: out = relu(z @ Wd + bd)
  gemm_mfma<1><<<gblocks, 256, 0, stream>>>(z, whd, wld, bd, out, N);
}

// Round 10
// 220.574 us; speedup vs baseline: 1.4164x; 1.1502x over previous
//
#include <hip/hip_runtime.h>

typedef long long i64;
typedef __attribute__((ext_vector_type(8))) short short8;
typedef __attribute__((ext_vector_type(8))) unsigned short us8;
typedef __attribute__((ext_vector_type(4))) unsigned short us4;
typedef __attribute__((ext_vector_type(4))) float f32x4;

__device__ __forceinline__ unsigned short bf16_rtn(float x) {
  unsigned u = __float_as_uint(x);
  unsigned r = (u + 0x7FFFu + ((u >> 16) & 1u)) >> 16;
  return (unsigned short)r;
}
__device__ __forceinline__ float bf16_to_f(unsigned short h) {
  return __uint_as_float(((unsigned)h) << 16);
}

// ---------------------------------------------------------------------------
// Per-wave edge-dtype detection (int64 storage => odd int32 words of row 0
// are all zero; for int32 data they are edge values, P(64 zeros) ~ 0).
// ---------------------------------------------------------------------------
__device__ __forceinline__ bool wave_is64(const int* __restrict__ ei32, i64 e0) {
  int probe = ei32[2 * e0 + 1];
  return __ballot(probe != 0) == 0ULL;
}

// ---------------------------------------------------------------------------
// init: zero counts[N] + weight split/transpose (3 weights) in one launch.
// W[128][128] fp32 -> WT hi/lo bf16 [c][k], W = hi + lo to ~2^-18 relative.
// ---------------------------------------------------------------------------
__global__ __launch_bounds__(256) void init_split_kernel(
    int* __restrict__ counts, int N,
    const float* __restrict__ Wa, unsigned short* __restrict__ wha, unsigned short* __restrict__ wla,
    const float* __restrict__ Wb, unsigned short* __restrict__ whb, unsigned short* __restrict__ wlb,
    const float* __restrict__ Wc, unsigned short* __restrict__ whc, unsigned short* __restrict__ wlc) {
  int nbInit = (N + 255) >> 8;
  if ((int)blockIdx.x < nbInit) {
    int i = blockIdx.x * 256 + threadIdx.x;
    if (i < N) counts[i] = 0;
    return;
  }
  int bb = blockIdx.x - nbInit;                   // 0..191
  int b = bb >> 6;
  int t = (bb & 63) * 256 + threadIdx.x;          // 0..16383
  const float* W = (b == 0) ? Wa : (b == 1) ? Wb : Wc;
  unsigned short* wh = (b == 0) ? wha : (b == 1) ? whb : whc;
  unsigned short* wl = (b == 0) ? wla : (b == 1) ? wlb : wlc;
  int c = t >> 7, k = t & 127;
  float w = W[k * 128 + c];
  unsigned short hi = bf16_rtn(w);
  unsigned short lo = bf16_rtn(w - bf16_to_f(hi));
  wh[c * 128 + k] = hi;
  wl[c * 128 + k] = lo;
}

// ---------------------------------------------------------------------------
// Narrow edge index to int32 once: s32[e], d32[e].
// ---------------------------------------------------------------------------
__global__ __launch_bounds__(256) void conv_edges_kernel(const int* __restrict__ ei32, int E,
                                                         int* __restrict__ s32, int* __restrict__ d32) {
  int e = blockIdx.x * 256 + threadIdx.x;
  if (e >= E) return;
  bool is64 = wave_is64(ei32, e);
  s32[e] = is64 ? ei32[2 * (i64)e] : ei32[e];
  d32[e] = is64 ? ei32[2 * ((i64)E + e)] : ei32[(i64)E + e];
}

// ---------------------------------------------------------------------------
// Destination-sharded degree count on narrowed d32.
// ---------------------------------------------------------------------------
__global__ __launch_bounds__(256) void count_kernel(const int* __restrict__ d32,
                                                    int* __restrict__ counts, int E, int N) {
  int shard = blockIdx.x & 7;
  int chunk = blockIdx.x >> 3;
  int ns = (N + 7) >> 3;
  int lo = shard * ns, hi = min(lo + ns, N);
  int base = chunk * 2048;
  int t = threadIdx.x;
#pragma unroll
  for (int j = 0; j < 8; ++j) {
    int e = base + j * 256 + t;
    if (e >= E) break;
    int d = d32[e];
    if (d >= lo && d < hi) atomicAdd(&counts[d], 1);
  }
}

// ---------------------------------------------------------------------------
// Device-wide exclusive scan of counts (3 phases, 1024 elems per block).
// ---------------------------------------------------------------------------
__global__ __launch_bounds__(256) void psum_kernel(const int* __restrict__ counts,
                                                   int* __restrict__ bsum, int N) {
  int base = blockIdx.x * 1024 + threadIdx.x * 4;
  int s = 0;
#pragma unroll
  for (int j = 0; j < 4; ++j) {
    int i = base + j;
    if (i < N) s += counts[i];
  }
#pragma unroll
  for (int off = 32; off > 0; off >>= 1) s += __shfl_down(s, off);
  __shared__ int ws[4];
  int wid = threadIdx.x >> 6;
  if ((threadIdx.x & 63) == 0) ws[wid] = s;
  __syncthreads();
  if (threadIdx.x == 0) bsum[blockIdx.x] = ws[0] + ws[1] + ws[2] + ws[3];
}

__global__ __launch_bounds__(1024) void bscan_kernel(int* __restrict__ bsum, int nb,
                                                     int* __restrict__ offs_last, int E) {
  __shared__ int sh[1024];
  int tid = threadIdx.x;
  int v = (tid < nb) ? bsum[tid] : 0;
  sh[tid] = v;
  __syncthreads();
  for (int off = 1; off < 1024; off <<= 1) {
    int t = (tid >= off) ? sh[tid - off] : 0;
    __syncthreads();
    sh[tid] += t;
    __syncthreads();
  }
  if (tid < nb) bsum[tid] = sh[tid] - v;  // exclusive
  if (tid == 0) offs_last[0] = E;
}

__global__ __launch_bounds__(256) void scatter_kernel(
    const int* __restrict__ counts, const int* __restrict__ bsum,
    int* __restrict__ offs, int* __restrict__ cursor, float* __restrict__ dinv, int N) {
  __shared__ int wsum[4];
  int tid = threadIdx.x;
  int base = blockIdx.x * 1024 + tid * 4;
  int c[4];
  int s = 0;
#pragma unroll
  for (int j = 0; j < 4; ++j) {
    int i = base + j;
    c[j] = (i < N) ? counts[i] : 0;
    s += c[j];
  }
  int lane = tid & 63, wid = tid >> 6;
  int incl = s;
#pragma unroll
  for (int off = 1; off < 64; off <<= 1) {
    int t = __shfl_up(incl, off);
    if (lane >= off) incl += t;
  }
  if (lane == 63) wsum[wid] = incl;
  __syncthreads();
  int wo = 0;
  for (int wq = 0; wq < wid; ++wq) wo += wsum[wq];
  int excl = incl - s + wo + bsum[blockIdx.x];
#pragma unroll
  for (int j = 0; j < 4; ++j) {
    int i = base + j;
    if (i < N) {
      offs[i] = excl;
      cursor[i] = excl;
      dinv[i] = rsqrtf((float)c[j] + 1.0f);
      excl += c[j];
    }
  }
}

// ---------------------------------------------------------------------------
// Destination-sharded CSR fill on narrowed s32/d32.
// ---------------------------------------------------------------------------
__global__ __launch_bounds__(256) void fill_kernel(const int* __restrict__ s32,
                                                   const int* __restrict__ d32,
                                                   int* __restrict__ cursor,
                                                   int* __restrict__ col, int E, int N) {
  int shard = blockIdx.x & 7;
  int chunk = blockIdx.x >> 3;
  int ns = (N + 7) >> 3;
  int lo = shard * ns, hi = min(lo + ns, N);
  int base = chunk * 2048;
  int t = threadIdx.x;
#pragma unroll
  for (int j = 0; j < 8; ++j) {
    int e = base + j * 256 + t;
    if (e >= E) break;
    int d = d32[e];
    if (d >= lo && d < hi) {
      int pos = atomicAdd(&cursor[d], 1);
      col[pos] = s32[e];
    }
  }
}

// ---------------------------------------------------------------------------
// LDS-free MFMA GEMM: C[N,128] = A[N,128] @ W[128,128], W pre-split hi+lo.
// ABF16=0: A fp32, split in registers, 3 passes (hh, lh, hl).
// ABF16=1: A bf16 (exact),            2 passes (h·Wh, h·Wl).
// OUT=0: hb bf16 [N][128] = acc * dinv[row]   OUT=1: fp32 relu(acc + bias)
// ---------------------------------------------------------------------------
template <int ABF16, int OUT>
__global__ __launch_bounds__(256, 4) void gemm_mfma(
    const void* __restrict__ Av, const unsigned short* __restrict__ WhT,
    const unsigned short* __restrict__ WlT, const float* __restrict__ aux,
    void* __restrict__ outv, int N) {
  int tid = threadIdx.x;
  int wid = tid >> 6, lane = tid & 63;
  int lr = lane & 15, kg = (lane >> 4) * 8;
  int rowbase = blockIdx.x * 128 + wid * 32;

  f32x4 acc[2][8];
#pragma unroll
  for (int tr = 0; tr < 2; ++tr)
#pragma unroll
    for (int tc = 0; tc < 8; ++tc) acc[tr][tc] = (f32x4){0.f, 0.f, 0.f, 0.f};

  int r[2] = {rowbase + lr, rowbase + 16 + lr};

  for (int kc = 0; kc < 128; kc += 32) {
    int k0 = kc + kg;
    short8 afh[2], afl[2];
#pragma unroll
    for (int tr = 0; tr < 2; ++tr) {
      if (ABF16) {
        const unsigned short* Ab = (const unsigned short*)Av;
        us8 v = {0, 0, 0, 0, 0, 0, 0, 0};
        if (r[tr] < N) v = *reinterpret_cast<const us8*>(&Ab[(i64)r[tr] * 128 + k0]);
#pragma unroll
        for (int j = 0; j < 8; ++j) afh[tr][j] = (short)v[j];
      } else {
        const float* A = (const float*)Av;
        float4 va = make_float4(0.f, 0.f, 0.f, 0.f), vb = va;
        if (r[tr] < N) {
          const float* p = &A[(i64)r[tr] * 128 + k0];
          va = *reinterpret_cast<const float4*>(p);
          vb = *reinterpret_cast<const float4*>(p + 4);
        }
        float xs[8] = {va.x, va.y, va.z, va.w, vb.x, vb.y, vb.z, vb.w};
#pragma unroll
        for (int j = 0; j < 8; ++j) {
          unsigned short h = bf16_rtn(xs[j]);
          afh[tr][j] = (short)h;
          afl[tr][j] = (short)bf16_rtn(xs[j] - bf16_to_f(h));
        }
      }
    }
#pragma unroll
    for (int tc = 0; tc < 8; ++tc) {
      int c = tc * 16 + lr;
      short8 bfh = *reinterpret_cast<const short8*>(&WhT[c * 128 + k0]);
      short8 bfl = *reinterpret_cast<const short8*>(&WlT[c * 128 + k0]);
#pragma unroll
      for (int tr = 0; tr < 2; ++tr) {
        acc[tr][tc] = __builtin_amdgcn_mfma_f32_16x16x32_bf16(afh[tr], bfh, acc[tr][tc], 0, 0, 0);
        acc[tr][tc] = __builtin_amdgcn_mfma_f32_16x16x32_bf16(afh[tr], bfl, acc[tr][tc], 0, 0, 0);
        if (!ABF16)
          acc[tr][tc] = __builtin_amdgcn_mfma_f32_16x16x32_bf16(afl[tr], bfh, acc[tr][tc], 0, 0, 0);
      }
    }
  }

  // epilogue (C/D layout: col = tc*16 + (lane&15), row = tr*16 + (lane>>4)*4 + reg)
  if (OUT == 0) {
    unsigned short* hb = (unsigned short*)outv;
#pragma unroll
    for (int tr = 0; tr < 2; ++tr) {
#pragma unroll
      for (int reg = 0; reg < 4; ++reg) {
        int row = rowbase + tr * 16 + (lane >> 4) * 4 + reg;
        if (row >= N) continue;
        float dv = aux[row];
#pragma unroll
        for (int tc = 0; tc < 8; ++tc) {
          int colg = tc * 16 + lr;
          hb[(i64)row * 128 + colg] = bf16_rtn(acc[tr][tc][reg] * dv);
        }
      }
    }
  } else {
    float* out = (float*)outv;
#pragma unroll
    for (int tr = 0; tr < 2; ++tr) {
#pragma unroll
      for (int reg = 0; reg < 4; ++reg) {
        int row = rowbase + tr * 16 + (lane >> 4) * 4 + reg;
        if (row >= N) continue;
#pragma unroll
        for (int tc = 0; tc < 8; ++tc) {
          int colg = tc * 16 + lr;
          out[(i64)row * 128 + colg] = fmaxf(acc[tr][tc][reg] + aux[colg], 0.f);
        }
      }
    }
  }
}

// ---------------------------------------------------------------------------
// Aggregation over bf16 H' [N][128]:
//   z[v] = bf16( (relu?)( dinv[v]*(H'[v] + sum_s H'[s]) + b ) )
// Half-wave (32 lanes) per node, lane = 4 channels (8B us4), unroll 4 for MLP.
// fp32 accumulate; bf16 nontemporal output (doesn't evict the gather lines).
// ---------------------------------------------------------------------------
template <int RELU>
__global__ __launch_bounds__(256) void agg_bf16(
    const unsigned short* __restrict__ hb, const int* __restrict__ col,
    const int* __restrict__ offs, const float* __restrict__ dinv,
    const float* __restrict__ bias, unsigned short* __restrict__ zout, int N) {
  i64 gt = (i64)blockIdx.x * blockDim.x + threadIdx.x;
  int gw = (int)(gt >> 6);
  int lane = threadIdx.x & 63;
  int v = gw * 2 + (lane >> 5);
  if (v >= N) return;
  int ch = (lane & 31) * 4;
  us4 sv = *reinterpret_cast<const us4*>(&hb[(i64)v * 128 + ch]);
  float a0 = bf16_to_f(sv[0]), a1 = bf16_to_f(sv[1]);
  float a2 = bf16_to_f(sv[2]), a3 = bf16_to_f(sv[3]);
  int beg = offs[v], end = offs[v + 1];
  int i = beg;
  for (; i + 3 < end; i += 4) {
    int s0 = col[i], s1 = col[i + 1], s2 = col[i + 2], s3 = col[i + 3];
    us4 u0 = *reinterpret_cast<const us4*>(&hb[(i64)s0 * 128 + ch]);
    us4 u1 = *reinterpret_cast<const us4*>(&hb[(i64)s1 * 128 + ch]);
    us4 u2 = *reinterpret_cast<const us4*>(&hb[(i64)s2 * 128 + ch]);
    us4 u3 = *reinterpret_cast<const us4*>(&hb[(i64)s3 * 128 + ch]);
    a0 += (bf16_to_f(u0[0]) + bf16_to_f(u1[0])) + (bf16_to_f(u2[0]) + bf16_to_f(u3[0]));
    a1 += (bf16_to_f(u0[1]) + bf16_to_f(u1[1])) + (bf16_to_f(u2[1]) + bf16_to_f(u3[1]));
    a2 += (bf16_to_f(u0[2]) + bf16_to_f(u1[2])) + (bf16_to_f(u2[2]) + bf16_to_f(u3[2]));
    a3 += (bf16_to_f(u0[3]) + bf16_to_f(u1[3])) + (bf16_to_f(u2[3]) + bf16_to_f(u3[3]));
  }
  for (; i < end; ++i) {
    int s0 = col[i];
    us4 u0 = *reinterpret_cast<const us4*>(&hb[(i64)s0 * 128 + ch]);
    a0 += bf16_to_f(u0[0]); a1 += bf16_to_f(u0[1]);
    a2 += bf16_to_f(u0[2]); a3 += bf16_to_f(u0[3]);
  }
  float dv = dinv[v];
  float4 b = *reinterpret_cast<const float4*>(&bias[ch]);
  float r0 = fmaf(a0, dv, b.x);
  float r1 = fmaf(a1, dv, b.y);
  float r2 = fmaf(a2, dv, b.z);
  float r3 = fmaf(a3, dv, b.w);
  if (RELU) {
    r0 = fmaxf(r0, 0.f); r1 = fmaxf(r1, 0.f);
    r2 = fmaxf(r2, 0.f); r3 = fmaxf(r3, 0.f);
  }
  us4 o;
  o[0] = bf16_rtn(r0); o[1] = bf16_rtn(r1);
  o[2] = bf16_rtn(r2); o[3] = bf16_rtn(r3);
  __builtin_nontemporal_store(o, reinterpret_cast<us4*>(&zout[(i64)v * 128 + ch]));
}

// ---------------------------------------------------------------------------
extern "C" void kernel_launch(void* const* d_in, const int* in_sizes, int n_in,
                              void* d_out, int out_size, void* d_ws, size_t ws_size,
                              hipStream_t stream) {
  const float* x  = (const float*)d_in[0];
  const int*   ei = (const int*)d_in[1];
  const float* W1 = (const float*)d_in[2];
  const float* b1 = (const float*)d_in[3];
  const float* W2 = (const float*)d_in[4];
  const float* b2 = (const float*)d_in[5];
  const float* Wd = (const float*)d_in[6];
  const float* bd = (const float*)d_in[7];
  int N = in_sizes[0] / 128;
  int E = in_sizes[1] / 2;
  float* out = (float*)d_out;

  // workspace layout
  char* w = (char*)d_ws;
  unsigned short* zb   = (unsigned short*)w;               // N*128 bf16 (12.8MB)
  unsigned short* wh1  = zb + (i64)N * 128;
  unsigned short* wl1  = wh1 + 16384;
  unsigned short* wh2  = wl1 + 16384;
  unsigned short* wl2  = wh2 + 16384;
  unsigned short* whd  = wl2 + 16384;
  unsigned short* wld  = whd + 16384;
  int*   counts = (int*)(wld + 16384);
  int*   offs   = counts + N;                              // N+1
  int*   cursor = offs + N + 1;                            // N
  int*   col    = cursor + N;                              // E
  int*   s32    = col + E;                                 // E
  int*   d32    = s32 + E;                                 // E
  float* dinv   = (float*)(d32 + E);                       // N
  int*   bsum   = (int*)(dinv + N);                        // <=1024
  unsigned short* hb = (unsigned short*)d_out;  // bf16 H' [N][128]; overwritten by decoder

  int nb = (N + 1023) / 1024;
  int nbInit = (N + 255) / 256;
  int cb = (E + 2047) / 2048;

  init_split_kernel<<<nbInit + 192, 256, 0, stream>>>(counts, N,
      W1, wh1, wl1, W2, wh2, wl2, Wd, whd, wld);
  conv_edges_kernel<<<(E + 255) / 256, 256, 0, stream>>>(ei, E, s32, d32);
  count_kernel<<<8 * cb, 256, 0, stream>>>(d32, counts, E, N);
  psum_kernel<<<nb, 256, 0, stream>>>(counts, bsum, N);
  bscan_kernel<<<1, 1024, 0, stream>>>(bsum, nb, offs + N, E);
  scatter_kernel<<<nb, 256, 0, stream>>>(counts, bsum, offs, cursor, dinv, N);
  fill_kernel<<<8 * cb, 256, 0, stream>>>(s32, d32, cursor, col, E, N);

  int gblocks = (N + 127) / 128;
  i64 aggthreads = (i64)((N + 1) / 2) * 64;
  int ablocks = (int)((aggthreads + 255) / 256);

  // conv1: hb = bf16((x@W1)*dinv) ; zb = bf16(relu(dinv*(hb_v + sum) + b1))
  gemm_mfma<0, 0><<<gblocks, 256, 0, stream>>>(x, wh1, wl1, dinv, hb, N);
  agg_bf16<1><<<ablocks, 256, 0, stream>>>(hb, col, offs, dinv, b1, zb, N);
  // conv2: hb = bf16((zb@W2)*dinv) ; zb = bf16(dinv*(hb_v + sum) + b2)
  gemm_mfma<1, 0><<<gblocks, 256, 0, stream>>>(zb, wh2, wl2, dinv, hb, N);
  agg_bf16<0><<<ablocks, 256, 0, stream>>>(hb, col, offs, dinv, b2, zb, N);
  // decoder: out = relu(zb @ Wd + bd)
  gemm_mfma<1, 1><<<gblocks, 256, 0, stream>>>(zb, whd, wld, bd, out, N);
}

// Round 11
// 207.178 us; speedup vs baseline: 1.5080x; 1.0647x over previous
//
#include <hip/hip_runtime.h>

typedef long long i64;
typedef __attribute__((ext_vector_type(8))) short short8;
typedef __attribute__((ext_vector_type(8))) unsigned short us8;
typedef __attribute__((ext_vector_type(4))) unsigned short us4;
typedef __attribute__((ext_vector_type(4))) float f32x4;

__device__ __forceinline__ unsigned short bf16_rtn(float x) {
  unsigned u = __float_as_uint(x);
  unsigned r = (u + 0x7FFFu + ((u >> 16) & 1u)) >> 16;
  return (unsigned short)r;
}
__device__ __forceinline__ float bf16_to_f(unsigned short h) {
  return __uint_as_float(((unsigned)h) << 16);
}

// Per-wave edge-dtype detection (int64 storage => odd int32 words are all 0).
__device__ __forceinline__ bool wave_is64(const int* __restrict__ ei32, i64 e0) {
  int probe = ei32[2 * e0 + 1];
  return __ballot(probe != 0) == 0ULL;
}

// ---------------------------------------------------------------------------
// init_all: one launch does (a) zero counts + done-flag, (b) weight
// split/transpose for 3 weights, (c) edge narrowing int64/int32 -> s32/d32.
// Block ranges: [0,nbInit) | [nbInit,nbInit+192) | [nbInit+192, +nbE)
// ---------------------------------------------------------------------------
__global__ __launch_bounds__(256) void init_all_kernel(
    int* __restrict__ counts, int N, int* __restrict__ done,
    const float* __restrict__ Wa, unsigned short* __restrict__ wha, unsigned short* __restrict__ wla,
    const float* __restrict__ Wb, unsigned short* __restrict__ whb, unsigned short* __restrict__ wlb,
    const float* __restrict__ Wc, unsigned short* __restrict__ whc, unsigned short* __restrict__ wlc,
    const int* __restrict__ ei32, int E, int* __restrict__ s32, int* __restrict__ d32) {
  int nbInit = (N + 255) >> 8;
  int bid = blockIdx.x;
  if (bid < nbInit) {
    int i = bid * 256 + threadIdx.x;
    if (i < N) counts[i] = 0;
    if (bid == 0 && threadIdx.x == 0) done[0] = 0;
    return;
  }
  bid -= nbInit;
  if (bid < 192) {
    int b = bid >> 6;
    int t = (bid & 63) * 256 + threadIdx.x;
    const float* W = (b == 0) ? Wa : (b == 1) ? Wb : Wc;
    unsigned short* wh = (b == 0) ? wha : (b == 1) ? whb : whc;
    unsigned short* wl = (b == 0) ? wla : (b == 1) ? wlb : wlc;
    int c = t >> 7, k = t & 127;
    float w = W[k * 128 + c];
    unsigned short hi = bf16_rtn(w);
    unsigned short lo = bf16_rtn(w - bf16_to_f(hi));
    wh[c * 128 + k] = hi;
    wl[c * 128 + k] = lo;
    return;
  }
  bid -= 192;
  int e = bid * 256 + threadIdx.x;
  if (e >= E) return;
  bool is64 = wave_is64(ei32, e);
  s32[e] = is64 ? ei32[2 * (i64)e] : ei32[e];
  d32[e] = is64 ? ei32[2 * ((i64)E + e)] : ei32[(i64)E + e];
}

// ---------------------------------------------------------------------------
// Destination-sharded degree count on narrowed d32 (shard = blockIdx&7,
// XCD-aligned under round-robin dispatch; perf heuristic only).
// ---------------------------------------------------------------------------
__global__ __launch_bounds__(256) void count_kernel(const int* __restrict__ d32,
                                                    int* __restrict__ counts, int E, int N) {
  int shard = blockIdx.x & 7;
  int chunk = blockIdx.x >> 3;
  int ns = (N + 7) >> 3;
  int lo = shard * ns, hi = min(lo + ns, N);
  int base = chunk * 2048;
  int t = threadIdx.x;
#pragma unroll
  for (int j = 0; j < 8; ++j) {
    int e = base + j * 256 + t;
    if (e >= E) break;
    int d = d32[e];
    if (d >= lo && d < hi) atomicAdd(&counts[d], 1);
  }
}

// ---------------------------------------------------------------------------
// Single-kernel device-wide exclusive scan (nb blocks, 1024 counts each).
// Publish per-block sums via device-scope atomics; spin on a done counter
// (nb ~= 49 blocks -> trivially all co-resident on 256 CUs); then every
// block independently sums its predecessors. No ordering assumptions.
// ---------------------------------------------------------------------------
__global__ __launch_bounds__(256) void scan_kernel(
    const int* __restrict__ counts, int* __restrict__ bsum, int* __restrict__ done,
    int* __restrict__ offs, int* __restrict__ cursor, float* __restrict__ dinv,
    int N, int nb, int E) {
  __shared__ int wsum[4];
  __shared__ int red[256];
  int tid = threadIdx.x;
  int b = blockIdx.x;
  int base = b * 1024 + tid * 4;
  int c[4];
  int s = 0;
#pragma unroll
  for (int j = 0; j < 4; ++j) {
    int i = base + j;
    c[j] = (i < N) ? counts[i] : 0;
    s += c[j];
  }
  int lane = tid & 63, wid = tid >> 6;
  int incl = s;
#pragma unroll
  for (int off = 1; off < 64; off <<= 1) {
    int t = __shfl_up(incl, off);
    if (lane >= off) incl += t;
  }
  if (lane == 63) wsum[wid] = incl;
  __syncthreads();
  int blocksum = wsum[0] + wsum[1] + wsum[2] + wsum[3];
  int wo = 0;
  for (int wq = 0; wq < wid; ++wq) wo += wsum[wq];
  int excl_in_block = incl - s + wo;

  // publish + wait for all blocks (device-scope atomics are XCD-coherent)
  if (tid == 0) {
    atomicExch(&bsum[b], blocksum);
    atomicAdd(done, 1);
    while (atomicAdd(done, 0) < nb) { }
  }
  __syncthreads();

  // this block's global offset = sum of bsum[0..b)
  int partial = 0;
  for (int t = tid; t < b; t += 256) partial += atomicAdd(&bsum[t], 0);
  red[tid] = partial;
  __syncthreads();
  for (int off = 128; off > 0; off >>= 1) {
    if (tid < off) red[tid] += red[tid + off];
    __syncthreads();
  }
  int excl = excl_in_block + red[0];

#pragma unroll
  for (int j = 0; j < 4; ++j) {
    int i = base + j;
    if (i < N) {
      offs[i] = excl;
      cursor[i] = excl;
      dinv[i] = rsqrtf((float)c[j] + 1.0f);
      excl += c[j];
    }
  }
  if (b == 0 && tid == 0) offs[N] = E;
}

// ---------------------------------------------------------------------------
// Destination-sharded CSR fill on narrowed s32/d32.
// ---------------------------------------------------------------------------
__global__ __launch_bounds__(256) void fill_kernel(const int* __restrict__ s32,
                                                   const int* __restrict__ d32,
                                                   int* __restrict__ cursor,
                                                   int* __restrict__ col, int E, int N) {
  int shard = blockIdx.x & 7;
  int chunk = blockIdx.x >> 3;
  int ns = (N + 7) >> 3;
  int lo = shard * ns, hi = min(lo + ns, N);
  int base = chunk * 2048;
  int t = threadIdx.x;
#pragma unroll
  for (int j = 0; j < 8; ++j) {
    int e = base + j * 256 + t;
    if (e >= E) break;
    int d = d32[e];
    if (d >= lo && d < hi) {
      int pos = atomicAdd(&cursor[d], 1);
      col[pos] = s32[e];
    }
  }
}

// ---------------------------------------------------------------------------
// LDS-free MFMA GEMM: C[N,128] = A[N,128] @ W[128,128], W pre-split hi+lo.
// ABF16=0: A fp32, split in registers, 3 passes.  ABF16=1: A bf16, 2 passes.
// OUT=0: hb bf16 [N][128] = acc * dinv[row]  (cached: agg gathers it next)
// OUT=1: out fp32 relu(acc + bias[col]), nontemporal (never re-read)
// ---------------------------------------------------------------------------
template <int ABF16, int OUT>
__global__ __launch_bounds__(256, 4) void gemm_mfma(
    const void* __restrict__ Av, const unsigned short* __restrict__ WhT,
    const unsigned short* __restrict__ WlT, const float* __restrict__ aux,
    void* __restrict__ outv, int N) {
  int tid = threadIdx.x;
  int wid = tid >> 6, lane = tid & 63;
  int lr = lane & 15, kg = (lane >> 4) * 8;
  int rowbase = blockIdx.x * 128 + wid * 32;

  f32x4 acc[2][8];
#pragma unroll
  for (int tr = 0; tr < 2; ++tr)
#pragma unroll
    for (int tc = 0; tc < 8; ++tc) acc[tr][tc] = (f32x4){0.f, 0.f, 0.f, 0.f};

  int r[2] = {rowbase + lr, rowbase + 16 + lr};

  for (int kc = 0; kc < 128; kc += 32) {
    int k0 = kc + kg;
    short8 afh[2], afl[2];
#pragma unroll
    for (int tr = 0; tr < 2; ++tr) {
      if (ABF16) {
        const unsigned short* Ab = (const unsigned short*)Av;
        us8 v = {0, 0, 0, 0, 0, 0, 0, 0};
        if (r[tr] < N) v = *reinterpret_cast<const us8*>(&Ab[(i64)r[tr] * 128 + k0]);
#pragma unroll
        for (int j = 0; j < 8; ++j) afh[tr][j] = (short)v[j];
      } else {
        const float* A = (const float*)Av;
        float4 va = make_float4(0.f, 0.f, 0.f, 0.f), vb = va;
        if (r[tr] < N) {
          const float* p = &A[(i64)r[tr] * 128 + k0];
          va = *reinterpret_cast<const float4*>(p);
          vb = *reinterpret_cast<const float4*>(p + 4);
        }
        float xs[8] = {va.x, va.y, va.z, va.w, vb.x, vb.y, vb.z, vb.w};
#pragma unroll
        for (int j = 0; j < 8; ++j) {
          unsigned short h = bf16_rtn(xs[j]);
          afh[tr][j] = (short)h;
          afl[tr][j] = (short)bf16_rtn(xs[j] - bf16_to_f(h));
        }
      }
    }
#pragma unroll
    for (int tc = 0; tc < 8; ++tc) {
      int c = tc * 16 + lr;
      short8 bfh = *reinterpret_cast<const short8*>(&WhT[c * 128 + k0]);
      short8 bfl = *reinterpret_cast<const short8*>(&WlT[c * 128 + k0]);
#pragma unroll
      for (int tr = 0; tr < 2; ++tr) {
        acc[tr][tc] = __builtin_amdgcn_mfma_f32_16x16x32_bf16(afh[tr], bfh, acc[tr][tc], 0, 0, 0);
        acc[tr][tc] = __builtin_amdgcn_mfma_f32_16x16x32_bf16(afh[tr], bfl, acc[tr][tc], 0, 0, 0);
        if (!ABF16)
          acc[tr][tc] = __builtin_amdgcn_mfma_f32_16x16x32_bf16(afl[tr], bfh, acc[tr][tc], 0, 0, 0);
      }
    }
  }

  // epilogue (C/D layout: col = tc*16 + (lane&15), row = tr*16 + (lane>>4)*4 + reg)
  if (OUT == 0) {
    unsigned short* hb = (unsigned short*)outv;
#pragma unroll
    for (int tr = 0; tr < 2; ++tr) {
#pragma unroll
      for (int reg = 0; reg < 4; ++reg) {
        int row = rowbase + tr * 16 + (lane >> 4) * 4 + reg;
        if (row >= N) continue;
        float dv = aux[row];
#pragma unroll
        for (int tc = 0; tc < 8; ++tc) {
          int colg = tc * 16 + lr;
          hb[(i64)row * 128 + colg] = bf16_rtn(acc[tr][tc][reg] * dv);
        }
      }
    }
  } else {
    float* out = (float*)outv;
#pragma unroll
    for (int tr = 0; tr < 2; ++tr) {
#pragma unroll
      for (int reg = 0; reg < 4; ++reg) {
        int row = rowbase + tr * 16 + (lane >> 4) * 4 + reg;
        if (row >= N) continue;
#pragma unroll
        for (int tc = 0; tc < 8; ++tc) {
          int colg = tc * 16 + lr;
          float v = fmaxf(acc[tr][tc][reg] + aux[colg], 0.f);
          __builtin_nontemporal_store(v, &out[(i64)row * 128 + colg]);
        }
      }
    }
  }
}

// ---------------------------------------------------------------------------
// Aggregation over bf16 H' [N][128]:
//   z[v] = bf16( (relu?)( dinv[v]*(H'[v] + sum_s H'[s]) + b ) )
// Quarter-wave (16 lanes) per node, lane = 8 channels (16B us8) -> half the
// gather-load instructions of the 8B version. 4 nodes/wave, unroll 4 for MLP.
// fp32 accumulate; bf16 nontemporal output.
// ---------------------------------------------------------------------------
template <int RELU>
__global__ __launch_bounds__(256) void agg_bf16(
    const unsigned short* __restrict__ hb, const int* __restrict__ col,
    const int* __restrict__ offs, const float* __restrict__ dinv,
    const float* __restrict__ bias, unsigned short* __restrict__ zout, int N) {
  int t = threadIdx.x;
  int lane = t & 63;
  int v = blockIdx.x * 16 + ((t >> 6) << 2) + (lane >> 4);  // 16 nodes/block
  int cl = lane & 15;                                       // 8 channels/lane
  if (v >= N) return;
  i64 base = (i64)v * 128 + cl * 8;
  us8 sv = *reinterpret_cast<const us8*>(&hb[base]);
  float a[8];
#pragma unroll
  for (int j = 0; j < 8; ++j) a[j] = bf16_to_f(sv[j]);

  int beg = offs[v], end = offs[v + 1];
  int i = beg;
  for (; i + 3 < end; i += 4) {
    int s0 = col[i], s1 = col[i + 1], s2 = col[i + 2], s3 = col[i + 3];
    us8 u0 = *reinterpret_cast<const us8*>(&hb[(i64)s0 * 128 + cl * 8]);
    us8 u1 = *reinterpret_cast<const us8*>(&hb[(i64)s1 * 128 + cl * 8]);
    us8 u2 = *reinterpret_cast<const us8*>(&hb[(i64)s2 * 128 + cl * 8]);
    us8 u3 = *reinterpret_cast<const us8*>(&hb[(i64)s3 * 128 + cl * 8]);
#pragma unroll
    for (int j = 0; j < 8; ++j)
      a[j] += (bf16_to_f(u0[j]) + bf16_to_f(u1[j])) + (bf16_to_f(u2[j]) + bf16_to_f(u3[j]));
  }
  for (; i < end; ++i) {
    int s0 = col[i];
    us8 u0 = *reinterpret_cast<const us8*>(&hb[(i64)s0 * 128 + cl * 8]);
#pragma unroll
    for (int j = 0; j < 8; ++j) a[j] += bf16_to_f(u0[j]);
  }

  float dv = dinv[v];
  f32x4 b0 = *reinterpret_cast<const f32x4*>(&bias[cl * 8]);
  f32x4 b1 = *reinterpret_cast<const f32x4*>(&bias[cl * 8 + 4]);
  float rbias[8] = {b0[0], b0[1], b0[2], b0[3], b1[0], b1[1], b1[2], b1[3]};
  us8 o;
#pragma unroll
  for (int j = 0; j < 8; ++j) {
    float r = fmaf(a[j], dv, rbias[j]);
    if (RELU) r = fmaxf(r, 0.f);
    o[j] = bf16_rtn(r);
  }
  __builtin_nontemporal_store(o, reinterpret_cast<us8*>(&zout[base]));
}

// ---------------------------------------------------------------------------
extern "C" void kernel_launch(void* const* d_in, const int* in_sizes, int n_in,
                              void* d_out, int out_size, void* d_ws, size_t ws_size,
                              hipStream_t stream) {
  const float* x  = (const float*)d_in[0];
  const int*   ei = (const int*)d_in[1];
  const float* W1 = (const float*)d_in[2];
  const float* b1 = (const float*)d_in[3];
  const float* W2 = (const float*)d_in[4];
  const float* b2 = (const float*)d_in[5];
  const float* Wd = (const float*)d_in[6];
  const float* bd = (const float*)d_in[7];
  int N = in_sizes[0] / 128;
  int E = in_sizes[1] / 2;
  float* out = (float*)d_out;

  // workspace layout
  char* w = (char*)d_ws;
  unsigned short* zb   = (unsigned short*)w;               // N*128 bf16 (12.8MB)
  unsigned short* wh1  = zb + (i64)N * 128;
  unsigned short* wl1  = wh1 + 16384;
  unsigned short* wh2  = wl1 + 16384;
  unsigned short* wl2  = wh2 + 16384;
  unsigned short* whd  = wl2 + 16384;
  unsigned short* wld  = whd + 16384;
  int*   counts = (int*)(wld + 16384);
  int*   offs   = counts + N;                              // N+1
  int*   cursor = offs + N + 1;                            // N
  int*   col    = cursor + N;                              // E
  int*   s32    = col + E;                                 // E
  int*   d32    = s32 + E;                                 // E
  float* dinv   = (float*)(d32 + E);                       // N
  int*   bsum   = (int*)(dinv + N);                        // <=1024
  int*   done   = bsum + 1024;                             // 1
  unsigned short* hb = (unsigned short*)d_out;  // bf16 H' [N][128]; overwritten by decoder

  int nb = (N + 1023) / 1024;
  int nbInit = (N + 255) / 256;
  int nbE = (E + 255) / 256;
  int cb = (E + 2047) / 2048;

  init_all_kernel<<<nbInit + 192 + nbE, 256, 0, stream>>>(counts, N, done,
      W1, wh1, wl1, W2, wh2, wl2, Wd, whd, wld, ei, E, s32, d32);
  count_kernel<<<8 * cb, 256, 0, stream>>>(d32, counts, E, N);
  scan_kernel<<<nb, 256, 0, stream>>>(counts, bsum, done, offs, cursor, dinv, N, nb, E);
  fill_kernel<<<8 * cb, 256, 0, stream>>>(s32, d32, cursor, col, E, N);

  int gblocks = (N + 127) / 128;
  int ablocks = (N + 15) / 16;

  // conv1: hb = bf16((x@W1)*dinv) ; zb = bf16(relu(dinv*(hb_v + sum) + b1))
  gemm_mfma<0, 0><<<gblocks, 256, 0, stream>>>(x, wh1, wl1, dinv, hb, N);
  agg_bf16<1><<<ablocks, 256, 0, stream>>>(hb, col, offs, dinv, b1, zb, N);
  // conv2: hb = bf16((zb@W2)*dinv) ; zb = bf16(dinv*(hb_v + sum) + b2)
  gemm_mfma<1, 0><<<gblocks, 256, 0, stream>>>(zb, wh2, wl2, dinv, hb, N);
  agg_bf16<0><<<ablocks, 256, 0, stream>>>(hb, col, offs, dinv, b2, zb, N);
  // decoder: out = relu(zb @ Wd + bd)
  gemm_mfma<1, 1><<<gblocks, 256, 0, stream>>>(zb, whd, wld, bd, out, N);
}